// Round 7
// baseline (810.740 us; speedup 1.0000x reference)
//
#include <hip/hip_runtime.h>
#include <math.h>

// ---------------- constants ----------------
#define T99   99
#define CC    256
#define NHH   8
#define FEAT  400
#define NS_   32
#define LSTEP 33

typedef __attribute__((ext_vector_type(8))) short s8v;   // 8 x bf16 (as raw u16)
typedef __attribute__((ext_vector_type(4))) float f4v;   // MFMA accumulator

// non-volatile: data deps preserve correctness, scheduler may interleave loads
__device__ __forceinline__ void mfma_bf16(f4v& d, s8v a, s8v b) {
  asm("v_mfma_f32_16x16x32_bf16 %0, %1, %2, %0" : "+v"(d) : "v"(a), "v"(b));
}

__device__ __forceinline__ unsigned short f2bf(float f) {
  union { float f; unsigned u; } x; x.f = f;
  unsigned r = x.u + 0x7FFFu + ((x.u >> 16) & 1u);
  return (unsigned short)(r >> 16);
}
__device__ __forceinline__ float bf2f(unsigned short h) {
  union { unsigned u; float f; } x; x.u = ((unsigned)h) << 16;
  return x.f;
}
__device__ __forceinline__ float blo(unsigned u) { union { unsigned x; float f; } c; c.x = u << 16; return c.f; }
__device__ __forceinline__ float bhi(unsigned u) { union { unsigned x; float f; } c; c.x = u & 0xffff0000u; return c.f; }

__device__ __forceinline__ float pe_val(int pos, int c) {
  int i = c >> 1;
  float freq = expf((float)(2 * i) * (-0.03597789207803197f)); // -ln(10000)/256
  float ang = (float)pos * freq;
  return (c & 1) ? cosf(ang) : sinf(ang);
}

// ---------------- conv stem ----------------
__global__ __launch_bounds__(128) void k_convbase(const float* __restrict__ x,
                                                  const float* __restrict__ w,
                                                  const float* __restrict__ bias,
                                                  float* __restrict__ base) {
  int b = blockIdx.x >> 8, co = blockIdx.x & 255, t = threadIdx.x;
  if (t >= T99) return;
  int g = co >> 6;
  float acc = bias[co];
  const float* xp = x + (size_t)(b * FEAT + g * 100) * T99;
  const float* wp = w + (size_t)co * 300;
  for (int ic = 0; ic < 100; ++ic) {
    float x0 = (t > 0)  ? xp[ic * T99 + t - 1] : 0.f;
    float x1 = xp[ic * T99 + t];
    float x2 = (t < 98) ? xp[ic * T99 + t + 1] : 0.f;
    acc += wp[ic * 3] * x0 + wp[ic * 3 + 1] * x1 + wp[ic * 3 + 2] * x2;
  }
  base[(size_t)(b * CC + co) * T99 + t] = fmaxf(acc, 0.f);
}

// ---------------- weight conversion to bf16 ----------------
__global__ __launch_bounds__(256) void k_convW(const float* __restrict__ qkv, const float* __restrict__ o,
                                               const float* __restrict__ l1, const float* __restrict__ l2,
                                               int L, unsigned short* __restrict__ dst) {
  int total = L * 786432;
  for (int idx = blockIdx.x * 256 + threadIdx.x; idx < total; idx += gridDim.x * 256) {
    int l = idx / 786432, r = idx % 786432;
    float v;
    if (r < 196608)      v = qkv[(size_t)l * 196608 + r];
    else if (r < 262144) v = o[(size_t)l * 65536 + (r - 196608)];
    else if (r < 524288) v = l1[(size_t)l * 262144 + (r - 262144)];
    else                 v = l2[(size_t)l * 262144 + (r - 524288)];
    dst[idx] = f2bf(v);
  }
}

// ---------------- build encoder inputs ----------------
__global__ __launch_bounds__(256) void k_build_xg(const float* __restrict__ base, float* __restrict__ xg,
                                                  unsigned short* __restrict__ xgb) {
  int idx = blockIdx.x * 256 + threadIdx.x;
  int t = idx >> 10, r = idx & 1023, b4 = r >> 8, c = r & 255;
  float v = (b4 < 2) ? base[(size_t)(b4 * CC + c) * T99 + t]
                     : base[(size_t)((b4 - 2) * CC + c) * T99 + (98 - t)];
  v += pe_val(t, c);
  xg[idx] = v; xgb[idx] = f2bf(v);
}

__global__ __launch_bounds__(256) void k_build_xl(const float* __restrict__ base, float* __restrict__ xl,
                                                  unsigned short* __restrict__ xlb) {
  int idx = blockIdx.x * 256 + threadIdx.x;
  int ls = idx / 1536, r = idx % 1536, j = r >> 8, c = r & 255;
  int g = j >> 1, b = j & 1, t = ls * 3 + g;
  float v = base[(size_t)(b * CC + c) * T99 + t] + pe_val(ls, c);
  xl[idx] = v; xlb[idx] = f2bf(v);
}

// ================= GEMM job (64x64 tile, bf16 MFMA, optional fused LN on A) =================
// flags: 1=relu, 2=residual R, 4=write bf16 Yb, 8=skip fp32 Yf, 16=LN-A (Aln fp32 + lng/lnb), 32=write xln (blockIdx.y==0)
struct GJob {
  const float* Aln; const unsigned short* Ab;
  const float* lng; const float* lnb;
  float* xln;
  const unsigned short* W; const float* bias;
  const float* R;
  float* Yf; unsigned short* Yb;
  int M, N, K, flags;
};

__device__ __forceinline__ void gemm_job(const GJob& j, int m0, int n0) {
  __shared__ __align__(16) unsigned short Al[64][40];
  __shared__ __align__(16) unsigned short Bl[64][40];
  __shared__ float lg[256], lb[256];
  int tid = threadIdx.x;
  int lane = tid & 63, w = tid >> 6, wm = w >> 1, wn = w & 1;
  int sp = tid >> 2, kc = (tid & 3) << 3;
  int row = m0 + sp;
  bool doLN = (j.flags & 16) != 0;
  float mu = 0.f, rstd = 0.f;
  if (doLN) {   // K == 256 on this path
    lg[tid] = j.lng[tid]; lb[tid] = j.lnb[tid];
    float s = 0.f, s2 = 0.f;
    if (row < j.M) {
      const float* yr = j.Aln + (size_t)row * 256 + kc;
#pragma unroll
      for (int k0 = 0; k0 < 8; ++k0)
#pragma unroll
        for (int q = 0; q < 8; ++q) { float v = yr[k0 * 32 + q]; s += v; s2 += v * v; }
    }
    s  += __shfl_xor(s, 1, 64);  s  += __shfl_xor(s, 2, 64);
    s2 += __shfl_xor(s2, 1, 64); s2 += __shfl_xor(s2, 2, 64);
    mu = s * (1.f / 256.f);
    float var = s2 * (1.f / 256.f) - mu * mu;
    rstd = rsqrtf(var + 1e-5f);
    __syncthreads();
  }

  f4v acc[2][2];
#pragma unroll
  for (int mt = 0; mt < 2; ++mt)
#pragma unroll
    for (int nt = 0; nt < 2; ++nt) acc[mt][nt] = (f4v){0.f, 0.f, 0.f, 0.f};

  for (int k0 = 0; k0 < j.K; k0 += 32) {
    s8v av = {0, 0, 0, 0, 0, 0, 0, 0};
    if (row < j.M) {
      if (doLN) {
        const float* yr = j.Aln + (size_t)row * 256 + k0 + kc;
        bool wr = (j.flags & 32) && blockIdx.y == 0;
#pragma unroll
        for (int q = 0; q < 8; ++q) {
          float v = (yr[q] - mu) * rstd * lg[k0 + kc + q] + lb[k0 + kc + q];
          av[q] = (short)f2bf(v);
          if (wr) j.xln[(size_t)row * 256 + k0 + kc + q] = v;
        }
      } else {
        av = *(const s8v*)&j.Ab[(size_t)row * j.K + k0 + kc];
      }
    }
    *(s8v*)&Al[sp][kc] = av;
    *(s8v*)&Bl[sp][kc] = *(const s8v*)&j.W[(size_t)(n0 + sp) * j.K + k0 + kc];
    __syncthreads();
    s8v af[2], bf[2];
#pragma unroll
    for (int mt = 0; mt < 2; ++mt)
      af[mt] = *(const s8v*)&Al[wm * 32 + mt * 16 + (lane & 15)][(lane >> 4) * 8];
#pragma unroll
    for (int nt = 0; nt < 2; ++nt)
      bf[nt] = *(const s8v*)&Bl[wn * 32 + nt * 16 + (lane & 15)][(lane >> 4) * 8];
#pragma unroll
    for (int mt = 0; mt < 2; ++mt)
#pragma unroll
      for (int nt = 0; nt < 2; ++nt) mfma_bf16(acc[mt][nt], af[mt], bf[nt]);
    __syncthreads();
  }
  asm volatile("s_nop 7\n\ts_nop 7\n\ts_nop 4");
#pragma unroll
  for (int mt = 0; mt < 2; ++mt) {
#pragma unroll
    for (int nt = 0; nt < 2; ++nt) {
      int col = n0 + wn * 32 + nt * 16 + (lane & 15);
      float bv = j.bias[col];
#pragma unroll
      for (int r = 0; r < 4; ++r) {
        int orow = m0 + wm * 32 + mt * 16 + (lane >> 4) * 4 + r;
        if (orow < j.M) {
          float v = acc[mt][nt][r] + bv;
          if (j.flags & 2) v += j.R[(size_t)orow * j.N + col];
          if (j.flags & 1) v = fmaxf(v, 0.f);
          if (!(j.flags & 8)) j.Yf[(size_t)orow * j.N + col] = v;
          if (j.flags & 4) j.Yb[(size_t)orow * j.N + col] = f2bf(v);
        }
      }
    }
  }
}

__global__ __launch_bounds__(256) void k_gemmj(GJob j) {
  if ((int)blockIdx.x * 64 >= j.M) return;
  gemm_job(j, blockIdx.x * 64, blockIdx.y * 64);
}

__global__ __launch_bounds__(256) void k_gemmj2(GJob j0, GJob j1) {
  if (blockIdx.z == 0) {
    if ((int)blockIdx.x * 64 >= j0.M) return;
    gemm_job(j0, blockIdx.x * 64, blockIdx.y * 64);
  } else {
    if ((int)blockIdx.x * 64 >= j1.M) return;
    gemm_job(j1, blockIdx.x * 64, blockIdx.y * 64);
  }
}

// ---------------- attention ----------------
__device__ __forceinline__ void attn_body(const unsigned short* __restrict__ qkv,
                                          unsigned short* __restrict__ attb,
                                          int T_, int B_, int bid) {
  __shared__ float qv[32];
  __shared__ float red[128];
  __shared__ float pv[128];
  int tid = threadIdx.x;
  int q = bid % T_;
  int h = (bid / T_) % NHH;
  int b = bid / (T_ * NHH);
  if (tid < 32) qv[tid] = bf2f(qkv[(size_t)(q * B_ + b) * 768 + h * 32 + tid]);
  __syncthreads();
  float s = -1e30f;
  if (tid < T_) {
    const unsigned short* kp = qkv + (size_t)(tid * B_ + b) * 768 + 256 + h * 32;
    float d = 0;
#pragma unroll
    for (int i = 0; i < 32; ++i) d += qv[i] * bf2f(kp[i]);
    s = d * 0.176776695296636881f; // 1/sqrt(32)
  }
  red[tid] = s; __syncthreads();
  for (int o = 64; o > 0; o >>= 1) { if (tid < o) red[tid] = fmaxf(red[tid], red[tid + o]); __syncthreads(); }
  float mx = red[0]; __syncthreads();
  float p = (tid < T_) ? expf(s - mx) : 0.f;
  pv[tid] = p; red[tid] = p; __syncthreads();
  for (int o = 64; o > 0; o >>= 1) { if (tid < o) red[tid] += red[tid + o]; __syncthreads(); }
  float denom = red[0];
  __syncthreads();
  // PV: 4-way split over k
  int d = tid & 31, part = tid >> 5;
  float o = 0.f;
  for (int k = part; k < T_; k += 4)
    o += pv[k] * bf2f(qkv[(size_t)(k * B_ + b) * 768 + 512 + h * 32 + d]);
  red[tid] = o; __syncthreads();
  if (tid < 32) {
    float t = red[tid] + red[tid + 32] + red[tid + 64] + red[tid + 96];
    attb[(size_t)(q * B_ + b) * 256 + h * 32 + tid] = f2bf(t / denom);
  }
}

__global__ __launch_bounds__(128) void k_attn(const unsigned short* __restrict__ qkv,
                                              unsigned short* __restrict__ attb, int T_, int B_) {
  attn_body(qkv, attb, T_, B_, blockIdx.x);
}

__global__ __launch_bounds__(128) void k_attn2(const unsigned short* __restrict__ qkv0,
                                               unsigned short* __restrict__ attb0, int T0, int B0,
                                               const unsigned short* __restrict__ qkv1,
                                               unsigned short* __restrict__ attb1, int T1, int B1) {
  int bid = blockIdx.x;
  if (blockIdx.z == 0) {
    if (bid >= B0 * NHH * T0) return;
    attn_body(qkv0, attb0, T0, B0, bid);
  } else {
    if (bid >= B1 * NHH * T1) return;
    attn_body(qkv1, attb1, T1, B1, bid);
  }
}

// ---------------- layer norm (final encoder LN only) ----------------
__device__ __forceinline__ void ln_body(const float* __restrict__ X, const float* __restrict__ g,
                                        const float* __restrict__ bb, float* __restrict__ Y, int tok) {
  __shared__ float rs[256], rq[256];
  int c = threadIdx.x;
  float v = X[(size_t)tok * 256 + c];
  rs[c] = v; rq[c] = v * v; __syncthreads();
  for (int o = 128; o > 0; o >>= 1) { if (c < o) { rs[c] += rs[c + o]; rq[c] += rq[c + o]; } __syncthreads(); }
  float mu = rs[0] * (1.f / 256.f);
  float var = rq[0] * (1.f / 256.f) - mu * mu;
  Y[(size_t)tok * 256 + c] = (v - mu) * rsqrtf(var + 1e-5f) * g[c] + bb[c];
}

__global__ __launch_bounds__(256) void k_ln2(const float* __restrict__ X0, const float* __restrict__ g0,
                                             const float* __restrict__ bb0, float* __restrict__ Y0, int n0,
                                             const float* __restrict__ X1, const float* __restrict__ g1,
                                             const float* __restrict__ bb1, float* __restrict__ Y1, int n1) {
  int tok = blockIdx.x;
  if (blockIdx.z == 0) { if (tok < n0) ln_body(X0, g0, bb0, Y0, tok); }
  else                 { if (tok < n1) ln_body(X1, g1, bb1, Y1, tok); }
}

// ---------------- combine ----------------
__global__ __launch_bounds__(256) void k_combine(const float* __restrict__ encl, const float* __restrict__ encg,
                                                 float* __restrict__ base2) {
  int idx = blockIdx.x * 256 + threadIdx.x;
  int t = idx % T99, c = (idx / T99) & 255, b = idx / (CC * T99);
  int ls = t / 3, g = t % 3;
  float v = encl[(size_t)(ls * 6 + g * 2 + b) * 256 + c]
          + encg[(size_t)(t * 4 + b) * 256 + c]
          + encg[(size_t)((98 - t) * 4 + 2 + b) * 256 + c];
  base2[idx] = v;
}

// ---------------- fused s-branch: grouped conv1d + relu + 1x1 + sigmoid ----------------
__global__ __launch_bounds__(256) void k_sfuse(const float* __restrict__ base2, const float* __restrict__ s1w,
                                               const float* __restrict__ s1b, const float* __restrict__ s2w,
                                               const float* __restrict__ s2b, float* __restrict__ out) {
  __shared__ float rs[256];
  int b = blockIdx.x / T99, t = blockIdx.x % T99, co = threadIdx.x;
  int g = co >> 6;
  float acc = s1b[co];
  const float* xp = base2 + (size_t)(b * CC + g * 64) * T99;
  const float* wp = s1w + (size_t)co * 192;
  for (int ic = 0; ic < 64; ++ic) {
    float x0 = (t > 0)  ? xp[ic * T99 + t - 1] : 0.f;
    float x1 = xp[ic * T99 + t];
    float x2 = (t < 98) ? xp[ic * T99 + t + 1] : 0.f;
    acc += wp[ic * 3] * x0 + wp[ic * 3 + 1] * x1 + wp[ic * 3 + 2] * x2;
  }
  rs[co] = fmaxf(acc, 0.f) * s2w[co];
  __syncthreads();
  for (int o = 128; o > 0; o >>= 1) { if (co < o) rs[co] += rs[co + o]; __syncthreads(); }
  if (co == 0) out[blockIdx.x] = 1.f / (1.f + expf(-(rs[0] + s2b[0])));
}

// ---------------- w3 transpose ----------------
__global__ __launch_bounds__(256) void k_w3t(const float* __restrict__ c3w, float* __restrict__ w3t) {
  int idx = blockIdx.x * 256 + threadIdx.x;
  int co = idx & 255, ci = (idx >> 8) & 255, n = idx >> 16;
  w3t[idx] = c3w[((size_t)(co << 8) + ci) * 32 + n];
}

// ---------------- Gb[n][t][co][b] bf16 + pad row ----------------
__global__ __launch_bounds__(256) void k_G(const float* __restrict__ w3t, const float* __restrict__ base2,
                                           unsigned short* __restrict__ Gb) {
  int tc = blockIdx.x, n = blockIdx.y, b = blockIdx.z;
  int co = threadIdx.x;
  int t0 = tc * 25;
  float acc[25];
#pragma unroll
  for (int q = 0; q < 25; ++q) acc[q] = 0.f;
  const float* w = w3t + (size_t)n * 65536 + co;
  const float* bs = base2 + (size_t)b * CC * T99 + t0;
  for (int ci = 0; ci < 256; ++ci) {
    float wv = w[(size_t)ci * 256];
#pragma unroll
    for (int q = 0; q < 25; ++q) acc[q] += wv * bs[ci * T99 + q];
  }
#pragma unroll
  for (int q = 0; q < 25; ++q) {
    int t = t0 + q;
    if (t < T99) Gb[((size_t)(n * T99 + t) * 256 + co) * 2 + b] = f2bf(acc[q]);
  }
  if (tc == 0 && n == 0 && b == 0)
    ((unsigned int*)(Gb + (size_t)NS_ * T99 * 512))[co] = 0u;
}

// ---------------- p_pre: split-k 256-thread version ----------------
__global__ __launch_bounds__(256) void k_ppre(const unsigned short* __restrict__ Gb,
                                              const float* __restrict__ c3b,
                                              unsigned int* __restrict__ pinb32) {
  __shared__ float w0s[96], w1s[96];
  __shared__ int   ofs[96];
  __shared__ float part[128][4];
  int e = blockIdx.x % T99, s = blockIdx.x / T99;
  int tid = threadIdx.x;
  if (s >= e) {
    if (tid < 128) {
      float z0 = fmaxf(c3b[2 * tid], 0.f), z1 = fmaxf(c3b[2 * tid + 1], 0.f);
      unsigned int zz = ((unsigned)f2bf(z1) << 16) | (unsigned)f2bf(z0);
      pinb32[((size_t)s * T99 + e) * 128 + tid] = zz;
      pinb32[((size_t)(T99 + s) * T99 + e) * 128 + tid] = zz;
    }
    return;
  }
  if (tid < 96) {
    double center = (double)(e - s + 1);
    double S = ((double)s - 0.5 * center) + ((2.0 * center - 1.0) / 95.0) * (double)tid;
    double dn = trunc(S);
    double dec = S - dn;
    int di = (int)dn;
    double uc = ceil(S);
    int ui = (int)uc;
    int n = tid / 3;
    float w0 = 0.f, w1 = 0.f;
    int r0 = 0;
    if (dn >= 0.0 && dn <= 98.0) {
      r0 = di;
      w0 = (float)((1.0 - dec) / 3.0);
      if (uc >= 0.0 && uc <= 98.0) {
        if (ui == di) w0 += (float)(dec / 3.0);
        else          w1  = (float)(dec / 3.0);
      }
    }
    w0s[tid] = w0; w1s[tid] = w1;
    ofs[tid] = (n * T99 + r0) * 1024;
  }
  __syncthreads();
  int ch = tid & 127, half = tid >> 7;
  float a00 = 0.f, a01 = 0.f, a10 = 0.f, a11 = 0.f;
  const char* basep = (const char*)Gb + ch * 8;
  int k0 = half * 48;
#pragma unroll 8
  for (int k = k0; k < k0 + 48; ++k) {
    float w0 = w0s[k], w1 = w1s[k];
    const uint2* p = (const uint2*)(basep + ofs[k]);
    uint2 u0 = p[0];
    uint2 u1 = p[128];
    a00 += w0 * blo(u0.x) + w1 * blo(u1.x);
    a01 += w0 * bhi(u0.x) + w1 * bhi(u1.x);
    a10 += w0 * blo(u0.y) + w1 * blo(u1.y);
    a11 += w0 * bhi(u0.y) + w1 * bhi(u1.y);
  }
  if (half) { part[ch][0] = a00; part[ch][1] = a01; part[ch][2] = a10; part[ch][3] = a11; }
  __syncthreads();
  if (tid < 128) {
    a00 += part[ch][0]; a01 += part[ch][1]; a10 += part[ch][2]; a11 += part[ch][3];
    float b0 = c3b[2 * tid], b1 = c3b[2 * tid + 1];
    unsigned int zb0 = ((unsigned)f2bf(fmaxf(a10 + b1, 0.f)) << 16) | (unsigned)f2bf(fmaxf(a00 + b0, 0.f));
    unsigned int zb1 = ((unsigned)f2bf(fmaxf(a11 + b1, 0.f)) << 16) | (unsigned)f2bf(fmaxf(a01 + b0, 0.f));
    pinb32[((size_t)s * T99 + e) * 128 + tid] = zb0;
    pinb32[((size_t)(T99 + s) * T99 + e) * 128 + tid] = zb1;
  }
}

// ---------------- weight pack for conv3x3 ----------------
__global__ __launch_bounds__(256) void k_wb2(const float* __restrict__ pw, unsigned short* __restrict__ wbf) {
  int idx = blockIdx.x * 256 + threadIdx.x;
  if (idx >= 73728) return;
  int lane = idx & 63;
  int cog  = (idx >> 6) & 15;
  int kst  = (idx >> 10) & 7;
  int tap  = idx >> 13;
  int co = cog * 16 + (lane & 15);
  int k  = kst * 32 + (lane >> 4) * 8;
  s8v v;
#pragma unroll
  for (int j = 0; j < 8; ++j)
    v[j] = (short)f2bf(pw[((size_t)co * 256 + k + j) * 9 + tap]);
  *(s8v*)&wbf[(size_t)idx * 8] = v;
}

// ---------------- const-vector for conv const-region ----------------
__global__ __launch_bounds__(256) void k_cvec(const float* __restrict__ pw, const float* __restrict__ cin,
                                              const float* __restrict__ bias, int reluCin,
                                              float* __restrict__ coutF, unsigned short* __restrict__ coutB) {
  __shared__ float rs[256];
  int co = blockIdx.x, ci = threadIdx.x;
  float c = cin[ci];
  if (reluCin) c = fmaxf(c, 0.f);
  const float* wp = pw + ((size_t)co * 256 + ci) * 9;
  float wsum = 0.f;
#pragma unroll
  for (int t = 0; t < 9; ++t) wsum += wp[t];
  rs[ci] = wsum * c;
  __syncthreads();
  for (int o = 128; o > 0; o >>= 1) { if (ci < o) rs[ci] += rs[ci + o]; __syncthreads(); }
  if (ci == 0) {
    float r = fmaxf(bias[co] + rs[0], 0.f);
    coutF[co] = r;
    coutB[co] = f2bf(r);
  }
}

// ---------------- 3x3 conv: halo-LDS, sw-pipelined MFMA, const-region skip ----------------
__device__ __forceinline__ int aoff(int s) {
  int tap = s >> 3, kst = s & 7;
  return ((tap / 3) * 10 + (tap % 3)) * 264 + kst * 32;
}
__device__ __forceinline__ void ldb4(const unsigned short* __restrict__ B0, int s, s8v* dst) {
#pragma unroll
  for (int nt = 0; nt < 4; ++nt) dst[nt] = *(const s8v*)(B0 + (size_t)s * 8192 + nt * 512);
}

__global__ __launch_bounds__(256) void k_conv3x3(const unsigned short* __restrict__ in,
                                                 const unsigned short* __restrict__ wbf,
                                                 const float* __restrict__ bias,
                                                 const unsigned short* __restrict__ cvecB,
                                                 int D, int lo, int hi,
                                                 unsigned short* __restrict__ out) {
  __shared__ __align__(16) unsigned short Ah[100 * 264];
  int b = blockIdx.z;
  int co0 = blockIdx.y * 128;
  int ti = blockIdx.x / 13, tj = blockIdx.x % 13;
  int i0 = ti * 8, j0 = tj * 8;
  int tid = threadIdx.x;

  if (i0 - 1 >= lo && i0 + 8 <= hi && j0 - 1 >= lo && j0 + 8 <= hi && i0 - 1 >= j0 + 8 + D) {
    const unsigned int* cv = (const unsigned int*)(cvecB + co0);
    unsigned int* ob = (unsigned int*)out;
#pragma unroll
    for (int r = 0; r < 16; ++r) {
      int idx = r * 256 + tid;
      int sp = idx >> 6, cp = idx & 63;
      int gi = i0 + (sp >> 3), gj = j0 + (sp & 7);
      ob[((size_t)(b * T99 + gi) * T99 + gj) * 128 + (co0 >> 1) + cp] = cv[cp];
    }
    return;
  }

#pragma unroll
  for (int it = 0; it < 13; ++it) {
    int chunk = it * 256 + tid;
    if (chunk < 3200) {
      int row = chunk >> 5;
      int cc = (chunk & 31) * 8;
      int gi = i0 + row / 10 - 1, gj = j0 + row % 10 - 1;
      s8v val = {0, 0, 0, 0, 0, 0, 0, 0};
      if (gi >= 0 && gi < T99 && gj >= 0 && gj < T99)
        val = *(const s8v*)&in[((size_t)(b * T99 + gi) * T99 + gj) * 256 + cc];
      *(s8v*)&Ah[row * 264 + cc] = val;
    }
  }
  __syncthreads();

  int lane = tid & 63, w = tid >> 6, wm = w >> 1, wn = w & 1;
  int l15 = lane & 15, lk = lane >> 4;
  int spL0 = wm * 32 + l15, spL1 = spL0 + 16;
  int hr0 = (spL0 >> 3) * 10 + (spL0 & 7);
  int hr1 = (spL1 >> 3) * 10 + (spL1 & 7);
  const unsigned short* A0 = &Ah[hr0 * 264 + lk * 8];
  const unsigned short* A1 = &Ah[hr1 * 264 + lk * 8];
  int cogbase = blockIdx.y * 8 + wn * 4;
  const unsigned short* B0 = wbf + (size_t)cogbase * 512 + (size_t)lane * 8;

  f4v acc[2][4];
#pragma unroll
  for (int mt = 0; mt < 2; ++mt)
#pragma unroll
    for (int nt = 0; nt < 4; ++nt) acc[mt][nt] = (f4v){0.f, 0.f, 0.f, 0.f};

  s8v a0c, a1c, a0n, a1n;
  s8v bq[3][4];
  a0c = *(const s8v*)(A0 + aoff(0));
  a1c = *(const s8v*)(A1 + aoff(0));
  a0n = a0c; a1n = a1c;
  ldb4(B0, 0, bq[0]);
  ldb4(B0, 1, bq[1]);
#pragma unroll
  for (int s = 0; s < 72; ++s) {
    if (s + 2 < 72) ldb4(B0, s + 2, bq[(s + 2) % 3]);
    if (s + 1 < 72) {
      a0n = *(const s8v*)(A0 + aoff(s + 1));
      a1n = *(const s8v*)(A1 + aoff(s + 1));
    }
#pragma unroll
    for (int nt = 0; nt < 4; ++nt) {
      mfma_bf16(acc[0][nt], a0c, bq[s % 3][nt]);
      mfma_bf16(acc[1][nt], a1c, bq[s % 3][nt]);
    }
    a0c = a0n; a1c = a1n;
  }

  asm volatile("s_nop 7\n\ts_nop 7\n\ts_nop 4");
#pragma unroll
  for (int mt = 0; mt < 2; ++mt) {
#pragma unroll
    for (int nt = 0; nt < 4; ++nt) {
      int co = co0 + wn * 64 + nt * 16 + l15;
      float bv = bias[co];
#pragma unroll
      for (int r = 0; r < 4; ++r) {
        int sp = wm * 32 + mt * 16 + lk * 4 + r;
        int gi = i0 + (sp >> 3), gj = j0 + (sp & 7);
        if (gi < T99 && gj < T99) {
          float v = fmaxf(acc[mt][nt][r] + bv, 0.f);
          out[((size_t)(b * T99 + gi) * T99 + gj) * 256 + co] = f2bf(v);
        }
      }
    }
  }
}

// ---------------- p3: both channels per row read ----------------
__global__ __launch_bounds__(256) void k_p3(const unsigned short* __restrict__ p2o,
                                            const float* __restrict__ w, const float* __restrict__ bias,
                                            float* __restrict__ cm) {
  int idx = blockIdx.x * 256 + threadIdx.x;   // [b][i][j]
  if (idx >= 2 * T99 * T99) return;
  int j = idx % T99, i = (idx / T99) % T99, b = idx / (T99 * T99);
  float a0 = bias[0], a1 = bias[1];
  const unsigned short* row = p2o + ((size_t)(b * T99 + i) * T99 + j) * 256;
  for (int c8 = 0; c8 < 256; c8 += 8) {
    s8v v = *(const s8v*)&row[c8];
#pragma unroll
    for (int q = 0; q < 8; ++q) {
      float x = bf2f((unsigned short)v[q]);
      a0 += w[c8 + q] * x;
      a1 += w[256 + c8 + q] * x;
    }
  }
  size_t base = (size_t)b * 2 * T99 * T99 + (size_t)i * T99 + j;
  cm[base] = 1.f / (1.f + expf(-a0));
  cm[base + T99 * T99] = 1.f / (1.f + expf(-a1));
}

// ---------------- host side ----------------
struct EncW {
  const float *qkvw, *qkvb, *ow, *ob, *l1w, *l1b, *l2w, *l2b, *n1g, *n1b, *n2g, *n2b, *nfg, *nfb;
};

struct EncBufs {
  const float* x0f; const unsigned short* x0b;
  float *y1, *y2, *xln, *xln1;
  unsigned short *qkvb, *attb, *hb;
  int M;
};

static GJob job_qkv(const EncW& W, const unsigned short* Wb, int l, const EncBufs& B) {
  GJob j = {};
  if (l == 0) { j.Ab = B.x0b; j.flags = 4 | 8; }
  else {
    j.Aln = B.y2; j.lng = W.n2g + (size_t)(l - 1) * 256; j.lnb = W.n2b + (size_t)(l - 1) * 256;
    j.xln = B.xln; j.flags = 4 | 8 | 16 | 32;
  }
  j.W = Wb + (size_t)l * 786432; j.bias = W.qkvb + (size_t)l * 768;
  j.Yb = B.qkvb; j.M = B.M; j.N = 768; j.K = 256;
  return j;
}
static GJob job_proj(const EncW& W, const unsigned short* Wb, int l, const EncBufs& B) {
  GJob j = {};
  j.Ab = B.attb;
  j.W = Wb + (size_t)l * 786432 + 196608; j.bias = W.ob + (size_t)l * 256;
  j.R = (l == 0) ? B.x0f : B.xln;
  j.Yf = B.y1; j.flags = 2; j.M = B.M; j.N = 256; j.K = 256;
  return j;
}
static GJob job_ffn1(const EncW& W, const unsigned short* Wb, int l, const EncBufs& B) {
  GJob j = {};
  j.Aln = B.y1; j.lng = W.n1g + (size_t)l * 256; j.lnb = W.n1b + (size_t)l * 256;
  j.xln = B.xln1;
  j.W = Wb + (size_t)l * 786432 + 262144; j.bias = W.l1b + (size_t)l * 1024;
  j.Yb = B.hb; j.flags = 1 | 4 | 8 | 16 | 32; j.M = B.M; j.N = 1024; j.K = 256;
  return j;
}
static GJob job_ffn2(const EncW& W, const unsigned short* Wb, int l, const EncBufs& B) {
  GJob j = {};
  j.Ab = B.hb;
  j.W = Wb + (size_t)l * 786432 + 524288; j.bias = W.l2b + (size_t)l * 256;
  j.R = B.xln1; j.Yf = B.y2; j.flags = 2; j.M = B.M; j.N = 256; j.K = 1024;
  return j;
}

extern "C" void kernel_launch(void* const* d_in, const int* in_sizes, int n_in,
                              void* d_out, int out_size, void* d_ws, size_t ws_size,
                              hipStream_t stream) {
  (void)in_sizes; (void)n_in; (void)out_size; (void)ws_size;
  const float* x    = (const float*)d_in[0];
  const float* cbw  = (const float*)d_in[1];
  const float* cbb  = (const float*)d_in[2];
  EncW tg = {(const float*)d_in[3],  (const float*)d_in[4],  (const float*)d_in[5],  (const float*)d_in[6],
             (const float*)d_in[7],  (const float*)d_in[8],  (const float*)d_in[9],  (const float*)d_in[10],
             (const float*)d_in[11], (const float*)d_in[12], (const float*)d_in[13], (const float*)d_in[14],
             (const float*)d_in[15], (const float*)d_in[16]};
  EncW tl = {(const float*)d_in[17], (const float*)d_in[18], (const float*)d_in[19], (const float*)d_in[20],
             (const float*)d_in[21], (const float*)d_in[22], (const float*)d_in[23], (const float*)d_in[24],
             (const float*)d_in[25], (const float*)d_in[26], (const float*)d_in[27], (const float*)d_in[28],
             (const float*)d_in[29], (const float*)d_in[30]};
  const float* s1w = (const float*)d_in[31];
  const float* s1b = (const float*)d_in[32];
  const float* s2w = (const float*)d_in[33];
  const float* s2b = (const float*)d_in[34];
  const float* c3w = (const float*)d_in[35];
  const float* c3b = (const float*)d_in[36];
  const float* p1w = (const float*)d_in[37];
  const float* p1b = (const float*)d_in[38];
  const float* p2w = (const float*)d_in[39];
  const float* p2b = (const float*)d_in[40];
  const float* p3w = (const float*)d_in[41];
  const float* p3b = (const float*)d_in[42];

  float* outp = (float*)d_out; // [cm 39204][start1 198]

  char* wp = (char*)d_ws;
  auto alloc = [&](size_t bytes) -> void* {
    void* p = (void*)wp;
    wp += (bytes + 255) & ~(size_t)255;
    return p;
  };
  float* base  = (float*)alloc(sizeof(float) * 2 * CC * T99);
  float* xg    = (float*)alloc(sizeof(float) * T99 * 4 * CC);
  float* xl    = (float*)alloc(sizeof(float) * LSTEP * 6 * CC);
  unsigned short* xgb = (unsigned short*)alloc(sizeof(short) * T99 * 4 * CC);
  unsigned short* xlb = (unsigned short*)alloc(sizeof(short) * LSTEP * 6 * CC);
  const int ML = 198, MG = 396;
  EncBufs BG, BL;
  BG.x0f = xg; BG.x0b = xgb; BG.M = MG;
  BL.x0f = xl; BL.x0b = xlb; BL.M = ML;
  BG.y1   = (float*)alloc(sizeof(float) * MG * 256);
  BG.y2   = (float*)alloc(sizeof(float) * MG * 256);
  BG.xln  = (float*)alloc(sizeof(float) * MG * 256);
  BG.xln1 = (float*)alloc(sizeof(float) * MG * 256);
  BG.qkvb = (unsigned short*)alloc(sizeof(short) * MG * 768);
  BG.attb = (unsigned short*)alloc(sizeof(short) * MG * 256);
  BG.hb   = (unsigned short*)alloc(sizeof(short) * MG * 1024);
  BL.y1   = (float*)alloc(sizeof(float) * ML * 256);
  BL.y2   = (float*)alloc(sizeof(float) * ML * 256);
  BL.xln  = (float*)alloc(sizeof(float) * ML * 256);
  BL.xln1 = (float*)alloc(sizeof(float) * ML * 256);
  BL.qkvb = (unsigned short*)alloc(sizeof(short) * ML * 768);
  BL.attb = (unsigned short*)alloc(sizeof(short) * ML * 256);
  BL.hb   = (unsigned short*)alloc(sizeof(short) * ML * 1024);
  float* encg  = (float*)alloc(sizeof(float) * MG * 256);
  float* encl  = (float*)alloc(sizeof(float) * ML * 256);
  float* base2 = (float*)alloc(sizeof(float) * 2 * CC * T99);
  float* w3t   = (float*)alloc(sizeof(float) * 32 * 256 * 256);
  unsigned short* Gb = (unsigned short*)alloc(sizeof(short) * (2 * NS_ * T99 * 256 + 512));
  unsigned short* pinb = (unsigned short*)alloc(sizeof(short) * 2 * T99 * T99 * 256);
  unsigned short* p1o  = (unsigned short*)alloc(sizeof(short) * 2 * T99 * T99 * 256);
  unsigned short* p2o  = (unsigned short*)alloc(sizeof(short) * 2 * T99 * T99 * 256);
  unsigned short* wb2a = (unsigned short*)alloc(sizeof(short) * 9 * 256 * 256);
  unsigned short* wb2b = (unsigned short*)alloc(sizeof(short) * 9 * 256 * 256);
  unsigned short* wtgb = (unsigned short*)alloc(sizeof(short) * 6 * 786432);
  unsigned short* wtlb = (unsigned short*)alloc(sizeof(short) * 3 * 786432);
  float* c1F = (float*)alloc(sizeof(float) * 256);
  unsigned short* c1B = (unsigned short*)alloc(sizeof(short) * 256);
  float* c2F = (float*)alloc(sizeof(float) * 256);
  unsigned short* c2B = (unsigned short*)alloc(sizeof(short) * 256);

  // 0. preamble
  k_convW<<<dim3(4096), dim3(256), 0, stream>>>(tg.qkvw, tg.ow, tg.l1w, tg.l2w, 6, wtgb);
  k_convW<<<dim3(2048), dim3(256), 0, stream>>>(tl.qkvw, tl.ow, tl.l1w, tl.l2w, 3, wtlb);
  k_w3t<<<dim3(8192), dim3(256), 0, stream>>>(c3w, w3t);
  k_wb2<<<dim3(288), dim3(256), 0, stream>>>(p1w, wb2a);
  k_wb2<<<dim3(288), dim3(256), 0, stream>>>(p2w, wb2b);
  k_cvec<<<dim3(256), dim3(256), 0, stream>>>(p1w, c3b, p1b, 1, c1F, c1B);
  k_cvec<<<dim3(256), dim3(256), 0, stream>>>(p2w, c1F, p2b, 0, c2F, c2B);
  // 1. conv stem + inputs
  k_convbase<<<dim3(512), dim3(128), 0, stream>>>(x, cbw, cbb, base);
  k_build_xl<<<dim3(198), dim3(256), 0, stream>>>(base, xl, xlb);
  k_build_xg<<<dim3(396), dim3(256), 0, stream>>>(base, xg, xgb);

  // 2. layers 0..2 merged (local || global)
  const int mgG = 7;
  for (int l = 0; l < 3; ++l) {
    k_gemmj2<<<dim3(mgG, 12, 2), dim3(256), 0, stream>>>(job_qkv(tl, wtlb, l, BL), job_qkv(tg, wtgb, l, BG));
    k_attn2<<<dim3(4 * NHH * T99, 1, 2), dim3(128), 0, stream>>>(BL.qkvb, BL.attb, LSTEP, 6,
                                                                 BG.qkvb, BG.attb, T99, 4);
    k_gemmj2<<<dim3(mgG, 4, 2), dim3(256), 0, stream>>>(job_proj(tl, wtlb, l, BL), job_proj(tg, wtgb, l, BG));
    k_gemmj2<<<dim3(mgG, 16, 2), dim3(256), 0, stream>>>(job_ffn1(tl, wtlb, l, BL), job_ffn1(tg, wtgb, l, BG));
    k_gemmj2<<<dim3(mgG, 4, 2), dim3(256), 0, stream>>>(job_ffn2(tl, wtlb, l, BL), job_ffn2(tg, wtgb, l, BG));
  }
  // 3. global layers 3..5
  for (int l = 3; l < 6; ++l) {
    k_gemmj<<<dim3(mgG, 12), dim3(256), 0, stream>>>(job_qkv(tg, wtgb, l, BG));
    k_attn<<<dim3(4 * NHH * T99), dim3(128), 0, stream>>>(BG.qkvb, BG.attb, T99, 4);
    k_gemmj<<<dim3(mgG, 4), dim3(256), 0, stream>>>(job_proj(tg, wtgb, l, BG));
    k_gemmj<<<dim3(mgG, 16), dim3(256), 0, stream>>>(job_ffn1(tg, wtgb, l, BG));
    k_gemmj<<<dim3(mgG, 4), dim3(256), 0, stream>>>(job_ffn2(tg, wtgb, l, BG));
  }
  // 4. final LNs
  k_ln2<<<dim3(MG, 1, 2), dim3(256), 0, stream>>>(BL.y2, tl.nfg, tl.nfb, encl, ML,
                                                  BG.y2, tg.nfg, tg.nfb, encg, MG);
  // 5. combine + s-branch
  k_combine<<<dim3(198), dim3(256), 0, stream>>>(encl, encg, base2);
  k_sfuse<<<dim3(198), dim3(256), 0, stream>>>(base2, s1w, s1b, s2w, s2b, outp + 2 * 2 * T99 * T99);
  // 6. bm + conv3d
  k_G<<<dim3(4, 32, 2), dim3(256), 0, stream>>>(w3t, base2, Gb);
  k_ppre<<<dim3(T99 * T99), dim3(256), 0, stream>>>(Gb, c3b, (unsigned int*)pinb);
  // 7. p-branch
  k_conv3x3<<<dim3(169, 2, 2), dim3(256), 0, stream>>>(pinb, wb2a, p1b, c1B, 0, 0, 98, p1o);
  k_conv3x3<<<dim3(169, 2, 2), dim3(256), 0, stream>>>(p1o, wb2b, p2b, c2B, 2, 1, 97, p2o);
  k_p3<<<dim3(77), dim3(256), 0, stream>>>(p2o, p3w, p3b, outp);
}

// Round 8
// 756.565 us; speedup vs baseline: 1.0716x; 1.0716x over previous
//
#include <hip/hip_runtime.h>
#include <math.h>

// ---------------- constants ----------------
#define T99   99
#define CC    256
#define NHH   8
#define FEAT  400
#define NS_   32
#define LSTEP 33

typedef __attribute__((ext_vector_type(8))) short s8v;   // 8 x bf16 (as raw u16)
typedef __attribute__((ext_vector_type(4))) float f4v;   // MFMA accumulator

// non-volatile asm: data deps preserve correctness, scheduler may interleave loads
__device__ __forceinline__ void mfma_bf16(f4v& d, s8v a, s8v b) {
  asm("v_mfma_f32_16x16x32_bf16 %0, %1, %2, %0" : "+v"(d) : "v"(a), "v"(b));
}

__device__ __forceinline__ unsigned short f2bf(float f) {
  union { float f; unsigned u; } x; x.f = f;
  unsigned r = x.u + 0x7FFFu + ((x.u >> 16) & 1u);
  return (unsigned short)(r >> 16);
}
__device__ __forceinline__ float bf2f(unsigned short h) {
  union { unsigned u; float f; } x; x.u = ((unsigned)h) << 16;
  return x.f;
}
__device__ __forceinline__ float blo(unsigned u) { union { unsigned x; float f; } c; c.x = u << 16; return c.f; }
__device__ __forceinline__ float bhi(unsigned u) { union { unsigned x; float f; } c; c.x = u & 0xffff0000u; return c.f; }

__device__ __forceinline__ float pe_val(int pos, int c) {
  int i = c >> 1;
  float freq = expf((float)(2 * i) * (-0.03597789207803197f)); // -ln(10000)/256
  float ang = (float)pos * freq;
  return (c & 1) ? cosf(ang) : sinf(ang);
}

// ---------------- conv stem ----------------
__global__ __launch_bounds__(128) void k_convbase(const float* __restrict__ x,
                                                  const float* __restrict__ w,
                                                  const float* __restrict__ bias,
                                                  float* __restrict__ base) {
  int b = blockIdx.x >> 8, co = blockIdx.x & 255, t = threadIdx.x;
  if (t >= T99) return;
  int g = co >> 6;
  float acc = bias[co];
  const float* xp = x + (size_t)(b * FEAT + g * 100) * T99;
  const float* wp = w + (size_t)co * 300;
  for (int ic = 0; ic < 100; ++ic) {
    float x0 = (t > 0)  ? xp[ic * T99 + t - 1] : 0.f;
    float x1 = xp[ic * T99 + t];
    float x2 = (t < 98) ? xp[ic * T99 + t + 1] : 0.f;
    acc += wp[ic * 3] * x0 + wp[ic * 3 + 1] * x1 + wp[ic * 3 + 2] * x2;
  }
  base[(size_t)(b * CC + co) * T99 + t] = fmaxf(acc, 0.f);
}

// ---------------- weight pack: fp32 {qkv,o,l1,l2} -> frag-order bf16 ----------------
// per layer blob = 98304 vec8. vec8 ranges: qkv[0,24576) o[24576,32768) l1[32768,65536) l2[65536,98304)
// per matrix (N,K): v -> lane=v&63, r=v>>6, kst=r%(K/32), cg=r/(K/32); co=cg*16+(lane&15), k=kst*32+(lane>>4)*8
__global__ __launch_bounds__(256) void k_wpackF(const float* __restrict__ qkv, const float* __restrict__ o,
                                                const float* __restrict__ l1, const float* __restrict__ l2,
                                                int L, unsigned short* __restrict__ dst) {
  int idx = blockIdx.x * 256 + threadIdx.x;
  if (idx >= L * 98304) return;
  int l = idx / 98304, v = idx % 98304;
  const float* src;
  int N, K, lv;
  if (v < 24576)      { src = qkv + (size_t)l * 196608; N = 768;  K = 256;  lv = v; }
  else if (v < 32768) { src = o   + (size_t)l * 65536;  N = 256;  K = 256;  lv = v - 24576; }
  else if (v < 65536) { src = l1  + (size_t)l * 262144; N = 1024; K = 256;  lv = v - 32768; }
  else                { src = l2  + (size_t)l * 262144; N = 256;  K = 1024; lv = v - 65536; }
  int lane = lv & 63, r = lv >> 6;
  int nkst = K >> 5;
  int kst = r % nkst, cg = r / nkst;
  int co = cg * 16 + (lane & 15);
  int k  = kst * 32 + (lane >> 4) * 8;
  const float* sp = src + (size_t)co * K + k;
  s8v out;
#pragma unroll
  for (int q = 0; q < 8; ++q) out[q] = (short)f2bf(sp[q]);
  *(s8v*)&dst[(size_t)idx * 8] = out;
}

// ---------------- build encoder inputs ----------------
__global__ __launch_bounds__(256) void k_build_xg(const float* __restrict__ base, float* __restrict__ xg,
                                                  unsigned short* __restrict__ xgb) {
  int idx = blockIdx.x * 256 + threadIdx.x;
  int t = idx >> 10, r = idx & 1023, b4 = r >> 8, c = r & 255;
  float v = (b4 < 2) ? base[(size_t)(b4 * CC + c) * T99 + t]
                     : base[(size_t)((b4 - 2) * CC + c) * T99 + (98 - t)];
  v += pe_val(t, c);
  xg[idx] = v; xgb[idx] = f2bf(v);
}

__global__ __launch_bounds__(256) void k_build_xl(const float* __restrict__ base, float* __restrict__ xl,
                                                  unsigned short* __restrict__ xlb) {
  int idx = blockIdx.x * 256 + threadIdx.x;
  int ls = idx / 1536, r = idx % 1536, j = r >> 8, c = r & 255;
  int g = j >> 1, b = j & 1, t = ls * 3 + g;
  float v = base[(size_t)(b * CC + c) * T99 + t] + pe_val(ls, c);
  xl[idx] = v; xlb[idx] = f2bf(v);
}

// ================= GEMM: full-K-chunk A staging, frag-packed B from global =================
// flags: 1=relu, 2=residual R, 4=write bf16 Yb, 8=skip fp32 Yf
struct GJ {
  const unsigned short* Ab;   // bf16 row-major [M][K]
  const unsigned short* Wf;   // frag-packed weights
  const float* bias;
  const float* R;
  float* Yf;
  unsigned short* Yb;
  int M, N, K, flags;
};

__device__ __forceinline__ void g_body(const GJ& j, int m0, int n0) {
  __shared__ __align__(16) unsigned short Al[64][264];
  int tid = threadIdx.x, lane = tid & 63, w = tid >> 6, wm = w >> 1, wn = w & 1;
  f4v acc[2][2];
#pragma unroll
  for (int mt = 0; mt < 2; ++mt)
#pragma unroll
    for (int nt = 0; nt < 2; ++nt) acc[mt][nt] = (f4v){0.f, 0.f, 0.f, 0.f};
  int nkst = j.K >> 5;
  for (int kc0 = 0; kc0 < j.K; kc0 += 256) {
    // stage A chunk 64x256 (one barrier)
#pragma unroll
    for (int it = 0; it < 8; ++it) {
      int idx = it * 256 + tid, row = idx >> 5, seg = idx & 31;
      s8v av = {0, 0, 0, 0, 0, 0, 0, 0};
      if (m0 + row < j.M) av = *(const s8v*)&j.Ab[(size_t)(m0 + row) * j.K + kc0 + seg * 8];
      *(s8v*)&Al[row][seg * 8] = av;
    }
    __syncthreads();
    int kb = kc0 >> 5;
#pragma unroll
    for (int kst = 0; kst < 8; ++kst) {
      s8v af[2], bf[2];
#pragma unroll
      for (int mt = 0; mt < 2; ++mt)
        af[mt] = *(const s8v*)&Al[wm * 32 + mt * 16 + (lane & 15)][kst * 32 + (lane >> 4) * 8];
#pragma unroll
      for (int nt = 0; nt < 2; ++nt) {
        int cg = (n0 >> 4) + wn * 2 + nt;
        bf[nt] = *(const s8v*)&j.Wf[((size_t)(cg * nkst + kb + kst) * 64 + lane) * 8];
      }
#pragma unroll
      for (int mt = 0; mt < 2; ++mt)
#pragma unroll
        for (int nt = 0; nt < 2; ++nt) mfma_bf16(acc[mt][nt], af[mt], bf[nt]);
    }
    __syncthreads();
  }
  asm volatile("s_nop 7\n\ts_nop 7\n\ts_nop 4");
#pragma unroll
  for (int mt = 0; mt < 2; ++mt) {
#pragma unroll
    for (int nt = 0; nt < 2; ++nt) {
      int col = n0 + wn * 32 + nt * 16 + (lane & 15);
      float bv = j.bias[col];
#pragma unroll
      for (int r = 0; r < 4; ++r) {
        int row = m0 + wm * 32 + mt * 16 + (lane >> 4) * 4 + r;
        if (row < j.M) {
          float v = acc[mt][nt][r] + bv;
          if (j.flags & 2) v += j.R[(size_t)row * j.N + col];
          if (j.flags & 1) v = fmaxf(v, 0.f);
          if (!(j.flags & 8)) j.Yf[(size_t)row * j.N + col] = v;
          if (j.flags & 4) j.Yb[(size_t)row * j.N + col] = f2bf(v);
        }
      }
    }
  }
}

__global__ __launch_bounds__(256) void k_g(GJ j) {
  if ((int)blockIdx.x * 64 >= j.M) return;
  g_body(j, blockIdx.x * 64, blockIdx.y * 64);
}

__global__ __launch_bounds__(256) void k_g2(GJ j0, GJ j1) {
  if (blockIdx.z == 0) {
    if ((int)blockIdx.x * 64 >= j0.M) return;
    g_body(j0, blockIdx.x * 64, blockIdx.y * 64);
  } else {
    if ((int)blockIdx.x * 64 >= j1.M) return;
    g_body(j1, blockIdx.x * 64, blockIdx.y * 64);
  }
}

// ---------------- attention (PV 4-way split) ----------------
__device__ __forceinline__ void attn_body(const unsigned short* __restrict__ qkv,
                                          unsigned short* __restrict__ attb,
                                          int T_, int B_, int bid) {
  __shared__ float qv[32];
  __shared__ float red[128];
  __shared__ float pv[128];
  int tid = threadIdx.x;
  int q = bid % T_;
  int h = (bid / T_) % NHH;
  int b = bid / (T_ * NHH);
  if (tid < 32) qv[tid] = bf2f(qkv[(size_t)(q * B_ + b) * 768 + h * 32 + tid]);
  __syncthreads();
  float s = -1e30f;
  if (tid < T_) {
    const unsigned short* kp = qkv + (size_t)(tid * B_ + b) * 768 + 256 + h * 32;
    float d = 0;
#pragma unroll
    for (int i = 0; i < 32; ++i) d += qv[i] * bf2f(kp[i]);
    s = d * 0.176776695296636881f; // 1/sqrt(32)
  }
  red[tid] = s; __syncthreads();
  for (int o = 64; o > 0; o >>= 1) { if (tid < o) red[tid] = fmaxf(red[tid], red[tid + o]); __syncthreads(); }
  float mx = red[0]; __syncthreads();
  float p = (tid < T_) ? expf(s - mx) : 0.f;
  pv[tid] = p; red[tid] = p; __syncthreads();
  for (int o = 64; o > 0; o >>= 1) { if (tid < o) red[tid] += red[tid + o]; __syncthreads(); }
  float denom = red[0];
  __syncthreads();
  int d = tid & 31, part = tid >> 5;
  float o = 0.f;
  for (int k = part; k < T_; k += 4)
    o += pv[k] * bf2f(qkv[(size_t)(k * B_ + b) * 768 + 512 + h * 32 + d]);
  red[tid] = o; __syncthreads();
  if (tid < 32) {
    float t = red[tid] + red[tid + 32] + red[tid + 64] + red[tid + 96];
    attb[(size_t)(q * B_ + b) * 256 + h * 32 + tid] = f2bf(t / denom);
  }
}

__global__ __launch_bounds__(128) void k_attn(const unsigned short* __restrict__ qkv,
                                              unsigned short* __restrict__ attb, int T_, int B_) {
  attn_body(qkv, attb, T_, B_, blockIdx.x);
}

__global__ __launch_bounds__(128) void k_attn2(const unsigned short* __restrict__ qkv0,
                                               unsigned short* __restrict__ attb0, int T0, int B0,
                                               const unsigned short* __restrict__ qkv1,
                                               unsigned short* __restrict__ attb1, int T1, int B1) {
  int bid = blockIdx.x;
  if (blockIdx.z == 0) {
    if (bid >= B0 * NHH * T0) return;
    attn_body(qkv0, attb0, T0, B0, bid);
  } else {
    if (bid >= B1 * NHH * T1) return;
    attn_body(qkv1, attb1, T1, B1, bid);
  }
}

// ---------------- layer norm (fp32 out + optional bf16 mirror) ----------------
__device__ __forceinline__ void ln_body(const float* __restrict__ X, const float* __restrict__ g,
                                        const float* __restrict__ bb, float* __restrict__ Y,
                                        unsigned short* __restrict__ Yb, int tok) {
  __shared__ float rs[256], rq[256];
  int c = threadIdx.x;
  float v = X[(size_t)tok * 256 + c];
  rs[c] = v; rq[c] = v * v; __syncthreads();
  for (int o = 128; o > 0; o >>= 1) { if (c < o) { rs[c] += rs[c + o]; rq[c] += rq[c + o]; } __syncthreads(); }
  float mu = rs[0] * (1.f / 256.f);
  float var = rq[0] * (1.f / 256.f) - mu * mu;
  float r = (v - mu) * rsqrtf(var + 1e-5f) * g[c] + bb[c];
  Y[(size_t)tok * 256 + c] = r;
  if (Yb) Yb[(size_t)tok * 256 + c] = f2bf(r);
}

__global__ __launch_bounds__(256) void k_ln(const float* __restrict__ X, const float* __restrict__ g,
                                            const float* __restrict__ bb, float* __restrict__ Y,
                                            unsigned short* __restrict__ Yb) {
  ln_body(X, g, bb, Y, Yb, blockIdx.x);
}

__global__ __launch_bounds__(256) void k_ln2(const float* __restrict__ X0, const float* __restrict__ g0,
                                             const float* __restrict__ bb0, float* __restrict__ Y0,
                                             unsigned short* __restrict__ Yb0, int n0,
                                             const float* __restrict__ X1, const float* __restrict__ g1,
                                             const float* __restrict__ bb1, float* __restrict__ Y1,
                                             unsigned short* __restrict__ Yb1, int n1) {
  int tok = blockIdx.x;
  if (blockIdx.z == 0) { if (tok < n0) ln_body(X0, g0, bb0, Y0, Yb0, tok); }
  else                 { if (tok < n1) ln_body(X1, g1, bb1, Y1, Yb1, tok); }
}

// ---------------- combine ----------------
__global__ __launch_bounds__(256) void k_combine(const float* __restrict__ encl, const float* __restrict__ encg,
                                                 float* __restrict__ base2) {
  int idx = blockIdx.x * 256 + threadIdx.x;
  int t = idx % T99, c = (idx / T99) & 255, b = idx / (CC * T99);
  int ls = t / 3, g = t % 3;
  float v = encl[(size_t)(ls * 6 + g * 2 + b) * 256 + c]
          + encg[(size_t)(t * 4 + b) * 256 + c]
          + encg[(size_t)((98 - t) * 4 + 2 + b) * 256 + c];
  base2[idx] = v;
}

// ---------------- fused s-branch ----------------
__global__ __launch_bounds__(256) void k_sfuse(const float* __restrict__ base2, const float* __restrict__ s1w,
                                               const float* __restrict__ s1b, const float* __restrict__ s2w,
                                               const float* __restrict__ s2b, float* __restrict__ out) {
  __shared__ float rs[256];
  int b = blockIdx.x / T99, t = blockIdx.x % T99, co = threadIdx.x;
  int g = co >> 6;
  float acc = s1b[co];
  const float* xp = base2 + (size_t)(b * CC + g * 64) * T99;
  const float* wp = s1w + (size_t)co * 192;
  for (int ic = 0; ic < 64; ++ic) {
    float x0 = (t > 0)  ? xp[ic * T99 + t - 1] : 0.f;
    float x1 = xp[ic * T99 + t];
    float x2 = (t < 98) ? xp[ic * T99 + t + 1] : 0.f;
    acc += wp[ic * 3] * x0 + wp[ic * 3 + 1] * x1 + wp[ic * 3 + 2] * x2;
  }
  rs[co] = fmaxf(acc, 0.f) * s2w[co];
  __syncthreads();
  for (int o = 128; o > 0; o >>= 1) { if (co < o) rs[co] += rs[co + o]; __syncthreads(); }
  if (co == 0) out[blockIdx.x] = 1.f / (1.f + expf(-(rs[0] + s2b[0])));
}

// ---------------- w3 transpose ----------------
__global__ __launch_bounds__(256) void k_w3t(const float* __restrict__ c3w, float* __restrict__ w3t) {
  int idx = blockIdx.x * 256 + threadIdx.x;
  int co = idx & 255, ci = (idx >> 8) & 255, n = idx >> 16;
  w3t[idx] = c3w[((size_t)(co << 8) + ci) * 32 + n];
}

// ---------------- Gb[n][t][co][b] bf16 + pad row ----------------
__global__ __launch_bounds__(256) void k_G(const float* __restrict__ w3t, const float* __restrict__ base2,
                                           unsigned short* __restrict__ Gb) {
  int tc = blockIdx.x, n = blockIdx.y, b = blockIdx.z;
  int co = threadIdx.x;
  int t0 = tc * 25;
  float acc[25];
#pragma unroll
  for (int q = 0; q < 25; ++q) acc[q] = 0.f;
  const float* w = w3t + (size_t)n * 65536 + co;
  const float* bs = base2 + (size_t)b * CC * T99 + t0;
  for (int ci = 0; ci < 256; ++ci) {
    float wv = w[(size_t)ci * 256];
#pragma unroll
    for (int q = 0; q < 25; ++q) acc[q] += wv * bs[ci * T99 + q];
  }
#pragma unroll
  for (int q = 0; q < 25; ++q) {
    int t = t0 + q;
    if (t < T99) Gb[((size_t)(n * T99 + t) * 256 + co) * 2 + b] = f2bf(acc[q]);
  }
  if (tc == 0 && n == 0 && b == 0)
    ((unsigned int*)(Gb + (size_t)NS_ * T99 * 512))[co] = 0u;
}

// ---------------- p_pre: split-k 256-thread ----------------
__global__ __launch_bounds__(256) void k_ppre(const unsigned short* __restrict__ Gb,
                                              const float* __restrict__ c3b,
                                              unsigned int* __restrict__ pinb32) {
  __shared__ float w0s[96], w1s[96];
  __shared__ int   ofs[96];
  __shared__ float part[128][4];
  int e = blockIdx.x % T99, s = blockIdx.x / T99;
  int tid = threadIdx.x;
  if (s >= e) {
    if (tid < 128) {
      float z0 = fmaxf(c3b[2 * tid], 0.f), z1 = fmaxf(c3b[2 * tid + 1], 0.f);
      unsigned int zz = ((unsigned)f2bf(z1) << 16) | (unsigned)f2bf(z0);
      pinb32[((size_t)s * T99 + e) * 128 + tid] = zz;
      pinb32[((size_t)(T99 + s) * T99 + e) * 128 + tid] = zz;
    }
    return;
  }
  if (tid < 96) {
    double center = (double)(e - s + 1);
    double S = ((double)s - 0.5 * center) + ((2.0 * center - 1.0) / 95.0) * (double)tid;
    double dn = trunc(S);
    double dec = S - dn;
    int di = (int)dn;
    double uc = ceil(S);
    int ui = (int)uc;
    int n = tid / 3;
    float w0 = 0.f, w1 = 0.f;
    int r0 = 0;
    if (dn >= 0.0 && dn <= 98.0) {
      r0 = di;
      w0 = (float)((1.0 - dec) / 3.0);
      if (uc >= 0.0 && uc <= 98.0) {
        if (ui == di) w0 += (float)(dec / 3.0);
        else          w1  = (float)(dec / 3.0);
      }
    }
    w0s[tid] = w0; w1s[tid] = w1;
    ofs[tid] = (n * T99 + r0) * 1024;
  }
  __syncthreads();
  int ch = tid & 127, half = tid >> 7;
  float a00 = 0.f, a01 = 0.f, a10 = 0.f, a11 = 0.f;
  const char* basep = (const char*)Gb + ch * 8;
  int k0 = half * 48;
#pragma unroll 8
  for (int k = k0; k < k0 + 48; ++k) {
    float w0 = w0s[k], w1 = w1s[k];
    const uint2* p = (const uint2*)(basep + ofs[k]);
    uint2 u0 = p[0];
    uint2 u1 = p[128];
    a00 += w0 * blo(u0.x) + w1 * blo(u1.x);
    a01 += w0 * bhi(u0.x) + w1 * bhi(u1.x);
    a10 += w0 * blo(u0.y) + w1 * blo(u1.y);
    a11 += w0 * bhi(u0.y) + w1 * bhi(u1.y);
  }
  if (half) { part[ch][0] = a00; part[ch][1] = a01; part[ch][2] = a10; part[ch][3] = a11; }
  __syncthreads();
  if (tid < 128) {
    a00 += part[ch][0]; a01 += part[ch][1]; a10 += part[ch][2]; a11 += part[ch][3];
    float b0 = c3b[2 * tid], b1 = c3b[2 * tid + 1];
    unsigned int zb0 = ((unsigned)f2bf(fmaxf(a10 + b1, 0.f)) << 16) | (unsigned)f2bf(fmaxf(a00 + b0, 0.f));
    unsigned int zb1 = ((unsigned)f2bf(fmaxf(a11 + b1, 0.f)) << 16) | (unsigned)f2bf(fmaxf(a01 + b0, 0.f));
    pinb32[((size_t)s * T99 + e) * 128 + tid] = zb0;
    pinb32[((size_t)(T99 + s) * T99 + e) * 128 + tid] = zb1;
  }
}

// ---------------- weight pack for conv3x3 ----------------
__global__ __launch_bounds__(256) void k_wb2(const float* __restrict__ pw, unsigned short* __restrict__ wbf) {
  int idx = blockIdx.x * 256 + threadIdx.x;
  if (idx >= 73728) return;
  int lane = idx & 63;
  int cog  = (idx >> 6) & 15;
  int kst  = (idx >> 10) & 7;
  int tap  = idx >> 13;
  int co = cog * 16 + (lane & 15);
  int k  = kst * 32 + (lane >> 4) * 8;
  s8v v;
#pragma unroll
  for (int j = 0; j < 8; ++j)
    v[j] = (short)f2bf(pw[((size_t)co * 256 + k + j) * 9 + tap]);
  *(s8v*)&wbf[(size_t)idx * 8] = v;
}

// ---------------- const-vector for conv const-region ----------------
__global__ __launch_bounds__(256) void k_cvec(const float* __restrict__ pw, const float* __restrict__ cin,
                                              const float* __restrict__ bias, int reluCin,
                                              float* __restrict__ coutF, unsigned short* __restrict__ coutB) {
  __shared__ float rs[256];
  int co = blockIdx.x, ci = threadIdx.x;
  float c = cin[ci];
  if (reluCin) c = fmaxf(c, 0.f);
  const float* wp = pw + ((size_t)co * 256 + ci) * 9;
  float wsum = 0.f;
#pragma unroll
  for (int t = 0; t < 9; ++t) wsum += wp[t];
  rs[ci] = wsum * c;
  __syncthreads();
  for (int o = 128; o > 0; o >>= 1) { if (ci < o) rs[ci] += rs[ci + o]; __syncthreads(); }
  if (ci == 0) {
    float r = fmaxf(bias[co] + rs[0], 0.f);
    coutF[co] = r;
    coutB[co] = f2bf(r);
  }
}

// ---------------- 3x3 conv: halo-LDS, sw-pipelined MFMA, const-region skip ----------------
__device__ __forceinline__ int aoff(int s) {
  int tap = s >> 3, kst = s & 7;
  return ((tap / 3) * 10 + (tap % 3)) * 264 + kst * 32;
}
__device__ __forceinline__ void ldb4(const unsigned short* __restrict__ B0, int s, s8v* dst) {
#pragma unroll
  for (int nt = 0; nt < 4; ++nt) dst[nt] = *(const s8v*)(B0 + (size_t)s * 8192 + nt * 512);
}

__global__ __launch_bounds__(256) void k_conv3x3(const unsigned short* __restrict__ in,
                                                 const unsigned short* __restrict__ wbf,
                                                 const float* __restrict__ bias,
                                                 const unsigned short* __restrict__ cvecB,
                                                 int D, int lo, int hi,
                                                 unsigned short* __restrict__ out) {
  __shared__ __align__(16) unsigned short Ah[100 * 264];
  int b = blockIdx.z;
  int co0 = blockIdx.y * 128;
  int ti = blockIdx.x / 13, tj = blockIdx.x % 13;
  int i0 = ti * 8, j0 = tj * 8;
  int tid = threadIdx.x;

  if (i0 - 1 >= lo && i0 + 8 <= hi && j0 - 1 >= lo && j0 + 8 <= hi && i0 - 1 >= j0 + 8 + D) {
    const unsigned int* cv = (const unsigned int*)(cvecB + co0);
    unsigned int* ob = (unsigned int*)out;
#pragma unroll
    for (int r = 0; r < 16; ++r) {
      int idx = r * 256 + tid;
      int sp = idx >> 6, cp = idx & 63;
      int gi = i0 + (sp >> 3), gj = j0 + (sp & 7);
      ob[((size_t)(b * T99 + gi) * T99 + gj) * 128 + (co0 >> 1) + cp] = cv[cp];
    }
    return;
  }

#pragma unroll
  for (int it = 0; it < 13; ++it) {
    int chunk = it * 256 + tid;
    if (chunk < 3200) {
      int row = chunk >> 5;
      int cc = (chunk & 31) * 8;
      int gi = i0 + row / 10 - 1, gj = j0 + row % 10 - 1;
      s8v val = {0, 0, 0, 0, 0, 0, 0, 0};
      if (gi >= 0 && gi < T99 && gj >= 0 && gj < T99)
        val = *(const s8v*)&in[((size_t)(b * T99 + gi) * T99 + gj) * 256 + cc];
      *(s8v*)&Ah[row * 264 + cc] = val;
    }
  }
  __syncthreads();

  int lane = tid & 63, w = tid >> 6, wm = w >> 1, wn = w & 1;
  int l15 = lane & 15, lk = lane >> 4;
  int spL0 = wm * 32 + l15, spL1 = spL0 + 16;
  int hr0 = (spL0 >> 3) * 10 + (spL0 & 7);
  int hr1 = (spL1 >> 3) * 10 + (spL1 & 7);
  const unsigned short* A0 = &Ah[hr0 * 264 + lk * 8];
  const unsigned short* A1 = &Ah[hr1 * 264 + lk * 8];
  int cogbase = blockIdx.y * 8 + wn * 4;
  const unsigned short* B0 = wbf + (size_t)cogbase * 512 + (size_t)lane * 8;

  f4v acc[2][4];
#pragma unroll
  for (int mt = 0; mt < 2; ++mt)
#pragma unroll
    for (int nt = 0; nt < 4; ++nt) acc[mt][nt] = (f4v){0.f, 0.f, 0.f, 0.f};

  s8v a0c, a1c, a0n, a1n;
  s8v bq[3][4];
  a0c = *(const s8v*)(A0 + aoff(0));
  a1c = *(const s8v*)(A1 + aoff(0));
  a0n = a0c; a1n = a1c;
  ldb4(B0, 0, bq[0]);
  ldb4(B0, 1, bq[1]);
#pragma unroll
  for (int s = 0; s < 72; ++s) {
    if (s + 2 < 72) ldb4(B0, s + 2, bq[(s + 2) % 3]);
    if (s + 1 < 72) {
      a0n = *(const s8v*)(A0 + aoff(s + 1));
      a1n = *(const s8v*)(A1 + aoff(s + 1));
    }
#pragma unroll
    for (int nt = 0; nt < 4; ++nt) {
      mfma_bf16(acc[0][nt], a0c, bq[s % 3][nt]);
      mfma_bf16(acc[1][nt], a1c, bq[s % 3][nt]);
    }
    a0c = a0n; a1c = a1n;
  }

  asm volatile("s_nop 7\n\ts_nop 7\n\ts_nop 4");
#pragma unroll
  for (int mt = 0; mt < 2; ++mt) {
#pragma unroll
    for (int nt = 0; nt < 4; ++nt) {
      int co = co0 + wn * 64 + nt * 16 + l15;
      float bv = bias[co];
#pragma unroll
      for (int r = 0; r < 4; ++r) {
        int sp = wm * 32 + mt * 16 + lk * 4 + r;
        int gi = i0 + (sp >> 3), gj = j0 + (sp & 7);
        if (gi < T99 && gj < T99) {
          float v = fmaxf(acc[mt][nt][r] + bv, 0.f);
          out[((size_t)(b * T99 + gi) * T99 + gj) * 256 + co] = f2bf(v);
        }
      }
    }
  }
}

// ---------------- p3: both channels per row ----------------
__global__ __launch_bounds__(256) void k_p3(const unsigned short* __restrict__ p2o,
                                            const float* __restrict__ w, const float* __restrict__ bias,
                                            float* __restrict__ cm) {
  int idx = blockIdx.x * 256 + threadIdx.x;
  if (idx >= 2 * T99 * T99) return;
  int j = idx % T99, i = (idx / T99) % T99, b = idx / (T99 * T99);
  float a0 = bias[0], a1 = bias[1];
  const unsigned short* row = p2o + ((size_t)(b * T99 + i) * T99 + j) * 256;
  for (int c8 = 0; c8 < 256; c8 += 8) {
    s8v v = *(const s8v*)&row[c8];
#pragma unroll
    for (int q = 0; q < 8; ++q) {
      float x = bf2f((unsigned short)v[q]);
      a0 += w[c8 + q] * x;
      a1 += w[256 + c8 + q] * x;
    }
  }
  size_t base = (size_t)b * 2 * T99 * T99 + (size_t)i * T99 + j;
  cm[base] = 1.f / (1.f + expf(-a0));
  cm[base + T99 * T99] = 1.f / (1.f + expf(-a1));
}

// ---------------- host ----------------
struct EncW {
  const float *qkvw, *qkvb, *ow, *ob, *l1w, *l1b, *l2w, *l2b, *n1g, *n1b, *n2g, *n2b, *nfg, *nfb;
};
struct EncBufs {
  float* x; unsigned short* xb;
  float* yb;
  unsigned short *qkvb, *attb, *hb;
  int M;
};

static GJ jqkv(const EncW& W, const unsigned short* Wp, int l, const EncBufs& B) {
  GJ j = {}; j.Ab = B.xb; j.Wf = Wp + (size_t)l * 786432;
  j.bias = W.qkvb + (size_t)l * 768; j.Yb = B.qkvb; j.flags = 4 | 8;
  j.M = B.M; j.N = 768; j.K = 256; return j;
}
static GJ jproj(const EncW& W, const unsigned short* Wp, int l, const EncBufs& B) {
  GJ j = {}; j.Ab = B.attb; j.Wf = Wp + (size_t)l * 786432 + 196608;
  j.bias = W.ob + (size_t)l * 256; j.R = B.x; j.Yf = B.yb; j.flags = 2;
  j.M = B.M; j.N = 256; j.K = 256; return j;
}
static GJ jffn1(const EncW& W, const unsigned short* Wp, int l, const EncBufs& B) {
  GJ j = {}; j.Ab = B.xb; j.Wf = Wp + (size_t)l * 786432 + 262144;
  j.bias = W.l1b + (size_t)l * 1024; j.Yb = B.hb; j.flags = 1 | 4 | 8;
  j.M = B.M; j.N = 1024; j.K = 256; return j;
}
static GJ jffn2(const EncW& W, const unsigned short* Wp, int l, const EncBufs& B) {
  GJ j = {}; j.Ab = B.hb; j.Wf = Wp + (size_t)l * 786432 + 524288;
  j.bias = W.l2b + (size_t)l * 256; j.R = B.x; j.Yf = B.yb; j.flags = 2;
  j.M = B.M; j.N = 256; j.K = 1024; return j;
}

extern "C" void kernel_launch(void* const* d_in, const int* in_sizes, int n_in,
                              void* d_out, int out_size, void* d_ws, size_t ws_size,
                              hipStream_t stream) {
  (void)in_sizes; (void)n_in; (void)out_size; (void)ws_size;
  const float* x    = (const float*)d_in[0];
  const float* cbw  = (const float*)d_in[1];
  const float* cbb  = (const float*)d_in[2];
  EncW tg = {(const float*)d_in[3],  (const float*)d_in[4],  (const float*)d_in[5],  (const float*)d_in[6],
             (const float*)d_in[7],  (const float*)d_in[8],  (const float*)d_in[9],  (const float*)d_in[10],
             (const float*)d_in[11], (const float*)d_in[12], (const float*)d_in[13], (const float*)d_in[14],
             (const float*)d_in[15], (const float*)d_in[16]};
  EncW tl = {(const float*)d_in[17], (const float*)d_in[18], (const float*)d_in[19], (const float*)d_in[20],
             (const float*)d_in[21], (const float*)d_in[22], (const float*)d_in[23], (const float*)d_in[24],
             (const float*)d_in[25], (const float*)d_in[26], (const float*)d_in[27], (const float*)d_in[28],
             (const float*)d_in[29], (const float*)d_in[30]};
  const float* s1w = (const float*)d_in[31];
  const float* s1b = (const float*)d_in[32];
  const float* s2w = (const float*)d_in[33];
  const float* s2b = (const float*)d_in[34];
  const float* c3w = (const float*)d_in[35];
  const float* c3b = (const float*)d_in[36];
  const float* p1w = (const float*)d_in[37];
  const float* p1b = (const float*)d_in[38];
  const float* p2w = (const float*)d_in[39];
  const float* p2b = (const float*)d_in[40];
  const float* p3w = (const float*)d_in[41];
  const float* p3b = (const float*)d_in[42];

  float* outp = (float*)d_out; // [cm 39204][start1 198]

  char* wp = (char*)d_ws;
  auto alloc = [&](size_t bytes) -> void* {
    void* p = (void*)wp;
    wp += (bytes + 255) & ~(size_t)255;
    return p;
  };
  float* base  = (float*)alloc(sizeof(float) * 2 * CC * T99);
  const int ML = 198, MG = 396;
  EncBufs BG, BL;
  BG.M = MG; BL.M = ML;
  BG.x  = (float*)alloc(sizeof(float) * MG * 256);
  BL.x  = (float*)alloc(sizeof(float) * ML * 256);
  BG.xb = (unsigned short*)alloc(sizeof(short) * MG * 256);
  BL.xb = (unsigned short*)alloc(sizeof(short) * ML * 256);
  BG.yb = (float*)alloc(sizeof(float) * MG * 256);
  BL.yb = (float*)alloc(sizeof(float) * ML * 256);
  BG.qkvb = (unsigned short*)alloc(sizeof(short) * MG * 768);
  BL.qkvb = (unsigned short*)alloc(sizeof(short) * ML * 768);
  BG.attb = (unsigned short*)alloc(sizeof(short) * MG * 256);
  BL.attb = (unsigned short*)alloc(sizeof(short) * ML * 256);
  BG.hb = (unsigned short*)alloc(sizeof(short) * MG * 1024);
  BL.hb = (unsigned short*)alloc(sizeof(short) * ML * 1024);
  float* encg  = (float*)alloc(sizeof(float) * MG * 256);
  float* encl  = (float*)alloc(sizeof(float) * ML * 256);
  float* base2 = (float*)alloc(sizeof(float) * 2 * CC * T99);
  float* w3t   = (float*)alloc(sizeof(float) * 32 * 256 * 256);
  unsigned short* Gb = (unsigned short*)alloc(sizeof(short) * (2 * NS_ * T99 * 256 + 512));
  unsigned short* pinb = (unsigned short*)alloc(sizeof(short) * 2 * T99 * T99 * 256);
  unsigned short* p1o  = (unsigned short*)alloc(sizeof(short) * 2 * T99 * T99 * 256);
  unsigned short* p2o  = (unsigned short*)alloc(sizeof(short) * 2 * T99 * T99 * 256);
  unsigned short* wb2a = (unsigned short*)alloc(sizeof(short) * 9 * 256 * 256);
  unsigned short* wb2b = (unsigned short*)alloc(sizeof(short) * 9 * 256 * 256);
  unsigned short* wpg  = (unsigned short*)alloc(sizeof(short) * 6 * 786432);
  unsigned short* wpl  = (unsigned short*)alloc(sizeof(short) * 3 * 786432);
  float* c1F = (float*)alloc(sizeof(float) * 256);
  unsigned short* c1B = (unsigned short*)alloc(sizeof(short) * 256);
  float* c2F = (float*)alloc(sizeof(float) * 256);
  unsigned short* c2B = (unsigned short*)alloc(sizeof(short) * 256);

  // 0. preamble: frag-pack all weights + conv packs + const vectors
  k_wpackF<<<dim3(2304), dim3(256), 0, stream>>>(tg.qkvw, tg.ow, tg.l1w, tg.l2w, 6, wpg);
  k_wpackF<<<dim3(1152), dim3(256), 0, stream>>>(tl.qkvw, tl.ow, tl.l1w, tl.l2w, 3, wpl);
  k_w3t<<<dim3(8192), dim3(256), 0, stream>>>(c3w, w3t);
  k_wb2<<<dim3(288), dim3(256), 0, stream>>>(p1w, wb2a);
  k_wb2<<<dim3(288), dim3(256), 0, stream>>>(p2w, wb2b);
  k_cvec<<<dim3(256), dim3(256), 0, stream>>>(p1w, c3b, p1b, 1, c1F, c1B);
  k_cvec<<<dim3(256), dim3(256), 0, stream>>>(p2w, c1F, p2b, 0, c2F, c2B);
  // 1. conv stem + encoder inputs
  k_convbase<<<dim3(512), dim3(128), 0, stream>>>(x, cbw, cbb, base);
  k_build_xl<<<dim3(198), dim3(256), 0, stream>>>(base, BL.x, BL.xb);
  k_build_xg<<<dim3(396), dim3(256), 0, stream>>>(base, BG.x, BG.xb);

  // 2. layers 0..2 merged (local || global)
  const int mgG = 7;
  for (int l = 0; l < 3; ++l) {
    k_g2<<<dim3(mgG, 12, 2), dim3(256), 0, stream>>>(jqkv(tl, wpl, l, BL), jqkv(tg, wpg, l, BG));
    k_attn2<<<dim3(4 * NHH * T99, 1, 2), dim3(128), 0, stream>>>(BL.qkvb, BL.attb, LSTEP, 6,
                                                                 BG.qkvb, BG.attb, T99, 4);
    k_g2<<<dim3(mgG, 4, 2), dim3(256), 0, stream>>>(jproj(tl, wpl, l, BL), jproj(tg, wpg, l, BG));
    k_ln2<<<dim3(MG, 1, 2), dim3(256), 0, stream>>>(BL.yb, tl.n1g + l * 256, tl.n1b + l * 256, BL.x, BL.xb, ML,
                                                    BG.yb, tg.n1g + l * 256, tg.n1b + l * 256, BG.x, BG.xb, MG);
    k_g2<<<dim3(mgG, 16, 2), dim3(256), 0, stream>>>(jffn1(tl, wpl, l, BL), jffn1(tg, wpg, l, BG));
    k_g2<<<dim3(mgG, 4, 2), dim3(256), 0, stream>>>(jffn2(tl, wpl, l, BL), jffn2(tg, wpg, l, BG));
    k_ln2<<<dim3(MG, 1, 2), dim3(256), 0, stream>>>(BL.yb, tl.n2g + l * 256, tl.n2b + l * 256, BL.x, BL.xb, ML,
                                                    BG.yb, tg.n2g + l * 256, tg.n2b + l * 256, BG.x, BG.xb, MG);
  }
  // 3. global layers 3..5
  for (int l = 3; l < 6; ++l) {
    k_g<<<dim3(mgG, 12), dim3(256), 0, stream>>>(jqkv(tg, wpg, l, BG));
    k_attn<<<dim3(4 * NHH * T99), dim3(128), 0, stream>>>(BG.qkvb, BG.attb, T99, 4);
    k_g<<<dim3(mgG, 4), dim3(256), 0, stream>>>(jproj(tg, wpg, l, BG));
    k_ln<<<dim3(MG), dim3(256), 0, stream>>>(BG.yb, tg.n1g + l * 256, tg.n1b + l * 256, BG.x, BG.xb);
    k_g<<<dim3(mgG, 16), dim3(256), 0, stream>>>(jffn1(tg, wpg, l, BG));
    k_g<<<dim3(mgG, 4), dim3(256), 0, stream>>>(jffn2(tg, wpg, l, BG));
    k_ln<<<dim3(MG), dim3(256), 0, stream>>>(BG.yb, tg.n2g + l * 256, tg.n2b + l * 256, BG.x, BG.xb);
  }
  // 4. final LNs
  k_ln2<<<dim3(MG, 1, 2), dim3(256), 0, stream>>>(BL.x, tl.nfg, tl.nfb, encl, nullptr, ML,
                                                  BG.x, tg.nfg, tg.nfb, encg, nullptr, MG);
  // 5. combine + s-branch
  k_combine<<<dim3(198), dim3(256), 0, stream>>>(encl, encg, base2);
  k_sfuse<<<dim3(198), dim3(256), 0, stream>>>(base2, s1w, s1b, s2w, s2b, outp + 2 * 2 * T99 * T99);
  // 6. bm + conv3d
  k_G<<<dim3(4, 32, 2), dim3(256), 0, stream>>>(w3t, base2, Gb);
  k_ppre<<<dim3(T99 * T99), dim3(256), 0, stream>>>(Gb, c3b, (unsigned int*)pinb);
  // 7. p-branch
  k_conv3x3<<<dim3(169, 2, 2), dim3(256), 0, stream>>>(pinb, wb2a, p1b, c1B, 0, 0, 98, p1o);
  k_conv3x3<<<dim3(169, 2, 2), dim3(256), 0, stream>>>(p1o, wb2b, p2b, c2B, 2, 1, 97, p2o);
  k_p3<<<dim3(77), dim3(256), 0, stream>>>(p2o, p3w, p3b, outp);
}